// Round 3
// baseline (480.134 us; speedup 1.0000x reference)
//
#include <hip/hip_runtime.h>
#include <hip/hip_bf16.h>

#define NPTS   6144
#define JPART  16                 // j-partitions across blocks
#define IBLK   128                // threads per block = i's per block
#define NIBLK  (NPTS / IBLK)      // 48 i-blocks
#define JLEN   (NPTS / JPART)     // 384 j's per partition
#define RESCALE (1.0f / 1024.0f)  // per-iteration overflow guard (cancels at final normalize)

// Pack f32 inputs into SoA for clean uniform loads; init v buffers.
__global__ __launch_bounds__(IBLK) void prep_kernel(
    const float* __restrict__ p2, const float* __restrict__ p3,
    float4* __restrict__ rec, float* __restrict__ z3a,
    float* __restrict__ vA, float* __restrict__ vB) {
  int i = blockIdx.x * IBLK + threadIdx.x;
  if (i >= NPTS) return;
  float x2 = p2[2 * i + 0];
  float y2 = p2[2 * i + 1];
  float x3 = p3[3 * i + 0];
  float y3 = p3[3 * i + 1];
  float z3 = p3[3 * i + 2];
  rec[i] = make_float4(x2, y2, x3, y3);
  z3a[i] = z3;
  vA[i] = 1.0f;   // v0 = ones
  vB[i] = 0.0f;   // iter0 atomic target
}

// y[i] += (1/1024) * sum_j S(i,j) * v[j], j in this block's partition.
// Also zeroes the buffer used as dst two iterations from now.
__global__ __launch_bounds__(IBLK) void matvec_kernel(
    const float4* __restrict__ rec, const float* __restrict__ z3a,
    const float* __restrict__ vsrc, float* __restrict__ vdst,
    float* __restrict__ vzero) {
  const int ib = blockIdx.x % NIBLK;
  const int jp = blockIdx.x / NIBLK;
  const int i  = ib * IBLK + threadIdx.x;

  if (jp == 0) vzero[i] = 0.0f;   // prepare next-next iteration's dst

  const float4 ri = rec[i];       // per-lane (vector) loads, once
  const float  zi = z3a[i];
  float acc = 0.0f;

  const int j0 = jp * JLEN;
#pragma unroll 8
  for (int jj = 0; jj < JLEN; ++jj) {
    const int j = j0 + jj;        // wave-uniform -> scalar/broadcast loads
    const float4 rj = rec[j];
    const float  zj = z3a[j];
    const float  vj = vsrc[j];
    float dx = ri.x - rj.x, dy = ri.y - rj.y;
    float a  = fmaf(dy, dy, dx * dx);                     // ||dp2||^2
    float ex = ri.z - rj.z, ey = ri.w - rj.w, ez = zi - zj;
    float b  = fmaf(ez, ez, fmaf(ey, ey, ex * ex));       // ||dp3||^2
    float s  = sqrtf(a * b);                              // d2*d3
    // (d2-d3)^2 = a + b - 2*sqrt(ab);  S = max(0, 1 - 100*(a+b) + 200*sqrt(ab))
    float w  = fmaf(a + b, -100.0f, 1.0f);
    w = fmaf(s, 200.0f, w);
    w = fmaxf(w, 0.0f);
    acc = fmaf(w, vj, acc);
  }
  atomicAdd(&vdst[i], acc * RESCALE);
}

// out = v / (||v||_2 + 1e-6), written as FLOAT32; each block redundantly
// computes the norm (6144 reads/block is trivial, avoids an extra launch).
__global__ __launch_bounds__(256) void finalize_kernel(
    const float* __restrict__ v, float* __restrict__ out) {
  const int tid = threadIdx.x;
  float ss = 0.0f;
  for (int k = tid; k < NPTS; k += 256) {
    float x = v[k];
    ss = fmaf(x, x, ss);
  }
  // wave (64) reduce, then across the 4 waves via LDS
  for (int off = 32; off > 0; off >>= 1) ss += __shfl_down(ss, off, 64);
  __shared__ float wsum[4];
  if ((tid & 63) == 0) wsum[tid >> 6] = ss;
  __syncthreads();
  float tot = wsum[0] + wsum[1] + wsum[2] + wsum[3];
  float inv = 1.0f / (sqrtf(tot) + 1e-6f);
  int i = blockIdx.x * 256 + tid;
  out[i] = v[i] * inv;
}

extern "C" void kernel_launch(void* const* d_in, const int* in_sizes, int n_in,
                              void* d_out, int out_size, void* d_ws, size_t ws_size,
                              hipStream_t stream) {
  const float* p2 = (const float*)d_in[0];   // 6144 x 2, float32
  const float* p3 = (const float*)d_in[1];   // 6144 x 3, float32
  float* out = (float*)d_out;                // 6144, float32

  float* w = (float*)d_ws;
  float4* rec = (float4*)w;           // 6144 float4  -> 24576 floats
  float*  z3a = w + 24576;            // 6144
  float*  buf[3] = { w + 32768, w + 40960, w + 49152 };  // v triple-buffer

  prep_kernel<<<NIBLK, IBLK, 0, stream>>>(p2, p3, rec, z3a, buf[0], buf[1]);

  for (int k = 0; k < 10; ++k) {
    float* vsrc  = buf[k % 3];
    float* vdst  = buf[(k + 1) % 3];
    float* vzero = buf[(k + 2) % 3];
    matvec_kernel<<<NIBLK * JPART, IBLK, 0, stream>>>(rec, z3a, vsrc, vdst, vzero);
  }

  // after 10 iters, result is in buf[(9+1)%3] == buf[1]
  finalize_kernel<<<NPTS / 256, 256, 0, stream>>>(buf[1], out);
}

// Round 4
// 286.405 us; speedup vs baseline: 1.6764x; 1.6764x over previous
//
#include <hip/hip_runtime.h>
#include <hip/hip_bf16.h>

#define NPTS   6144
#define IPT    4                  // i's per thread (register tile)
#define IBLK   128                // threads per block
#define ISPAN  (IBLK * IPT)       // 512 i's per block
#define NIBLK  (NPTS / ISPAN)     // 12 i-blocks
#define JPART  96                 // j-partitions across blocks
#define JLEN   (NPTS / JPART)     // 64 j's per partition
#define RESCALE (1.0f / 1024.0f)  // per-iteration overflow guard (cancels at final normalize)

// Pack f32 inputs into SoA for clean uniform loads; init v buffers.
__global__ __launch_bounds__(IBLK) void prep_kernel(
    const float* __restrict__ p2, const float* __restrict__ p3,
    float4* __restrict__ rec, float* __restrict__ z3a,
    float* __restrict__ vA, float* __restrict__ vB) {
  int i = blockIdx.x * IBLK + threadIdx.x;
  if (i >= NPTS) return;
  float x2 = p2[2 * i + 0];
  float y2 = p2[2 * i + 1];
  float x3 = p3[3 * i + 0];
  float y3 = p3[3 * i + 1];
  float z3 = p3[3 * i + 2];
  rec[i] = make_float4(x2, y2, x3, y3);
  z3a[i] = z3;
  vA[i] = 1.0f;   // v0 = ones
  vB[i] = 0.0f;   // iter0 atomic target
}

// y[i] += (1/1024) * sum_j S(i,j) * v[j], j in this block's partition.
// Each thread owns IPT=4 i-rows: amortizes the uniform j-side loads 4x and
// provides 4 independent FMA chains to cover VALU dep latency at low occupancy.
// Also zeroes the buffer used as dst two iterations from now.
__global__ __launch_bounds__(IBLK) void matvec_kernel(
    const float4* __restrict__ rec, const float* __restrict__ z3a,
    const float* __restrict__ vsrc, float* __restrict__ vdst,
    float* __restrict__ vzero) {
  const int ib = blockIdx.x % NIBLK;
  const int jp = blockIdx.x / NIBLK;
  const int i0 = ib * ISPAN + threadIdx.x;

  float4 ri[IPT];
  float  zi[IPT];
  float  acc[IPT];
#pragma unroll
  for (int u = 0; u < IPT; ++u) {
    const int i = i0 + u * IBLK;
    ri[u]  = rec[i];
    zi[u]  = z3a[i];
    acc[u] = 0.0f;
    if (jp == 0) vzero[i] = 0.0f;   // prepare next-next iteration's dst
  }

  const int j0 = jp * JLEN;
#pragma unroll 4
  for (int jj = 0; jj < JLEN; ++jj) {
    const int j = j0 + jj;          // wave-uniform -> scalar/broadcast loads
    const float4 rj = rec[j];
    const float  zj = z3a[j];
    const float  vj = vsrc[j];
#pragma unroll
    for (int u = 0; u < IPT; ++u) {
      float dx = ri[u].x - rj.x, dy = ri[u].y - rj.y;
      float a  = fmaf(dy, dy, dx * dx);                     // ||dp2||^2
      float ex = ri[u].z - rj.z, ey = ri[u].w - rj.w, ez = zi[u] - zj;
      float b  = fmaf(ez, ez, fmaf(ey, ey, ex * ex));       // ||dp3||^2
      float s  = __builtin_amdgcn_sqrtf(a * b);             // bare v_sqrt_f32 (~1 ulp)
      // (d2-d3)^2 = a + b - 2*sqrt(ab);  S = max(0, 1 - 100*(a+b) + 200*sqrt(ab))
      float w  = fmaf(a + b, -100.0f, 1.0f);
      w = fmaf(s, 200.0f, w);
      w = fmaxf(w, 0.0f);
      acc[u] = fmaf(w, vj, acc[u]);
    }
  }
#pragma unroll
  for (int u = 0; u < IPT; ++u)
    atomicAdd(&vdst[i0 + u * IBLK], acc[u] * RESCALE);
}

// out = v / (||v||_2 + 1e-6), float32; each block redundantly computes the norm.
__global__ __launch_bounds__(256) void finalize_kernel(
    const float* __restrict__ v, float* __restrict__ out) {
  const int tid = threadIdx.x;
  float ss = 0.0f;
  for (int k = tid; k < NPTS; k += 256) {
    float x = v[k];
    ss = fmaf(x, x, ss);
  }
  for (int off = 32; off > 0; off >>= 1) ss += __shfl_down(ss, off, 64);
  __shared__ float wsum[4];
  if ((tid & 63) == 0) wsum[tid >> 6] = ss;
  __syncthreads();
  float tot = wsum[0] + wsum[1] + wsum[2] + wsum[3];
  float inv = 1.0f / (sqrtf(tot) + 1e-6f);
  int i = blockIdx.x * 256 + tid;
  out[i] = v[i] * inv;
}

extern "C" void kernel_launch(void* const* d_in, const int* in_sizes, int n_in,
                              void* d_out, int out_size, void* d_ws, size_t ws_size,
                              hipStream_t stream) {
  const float* p2 = (const float*)d_in[0];   // 6144 x 2, float32
  const float* p3 = (const float*)d_in[1];   // 6144 x 3, float32
  float* out = (float*)d_out;                // 6144, float32

  float* w = (float*)d_ws;
  float4* rec = (float4*)w;           // 6144 float4  -> 24576 floats
  float*  z3a = w + 24576;            // 6144
  float*  buf[3] = { w + 32768, w + 40960, w + 49152 };  // v triple-buffer

  prep_kernel<<<NPTS / IBLK, IBLK, 0, stream>>>(p2, p3, rec, z3a, buf[0], buf[1]);

  for (int k = 0; k < 10; ++k) {
    float* vsrc  = buf[k % 3];
    float* vdst  = buf[(k + 1) % 3];
    float* vzero = buf[(k + 2) % 3];
    matvec_kernel<<<NIBLK * JPART, IBLK, 0, stream>>>(rec, z3a, vsrc, vdst, vzero);
  }

  // after 10 iters, result is in buf[(9+1)%3] == buf[1]
  finalize_kernel<<<NPTS / 256, 256, 0, stream>>>(buf[1], out);
}

// Round 5
// 246.142 us; speedup vs baseline: 1.9506x; 1.1636x over previous
//
#include <hip/hip_runtime.h>
#include <hip/hip_bf16.h>

#define NPTS   6144
#define IPT    4                  // i's per thread (register tile)
#define IBLK   128                // threads per block
#define ISPAN  (IBLK * IPT)       // 512 i's per block
#define NIBLK  (NPTS / ISPAN)     // 12 i-blocks
#define JPART  192                // j-partitions across blocks -> 2304 blocks, 4.5 waves/SIMD
#define JLEN   (NPTS / JPART)     // 32 j's per partition
#define RESCALE (1.0f / 1024.0f)  // per-iteration overflow guard (cancels at final normalize)

// Pack f32 inputs into SoA for clean uniform loads; init v buffers.
__global__ __launch_bounds__(IBLK) void prep_kernel(
    const float* __restrict__ p2, const float* __restrict__ p3,
    float4* __restrict__ rec, float* __restrict__ z3a,
    float* __restrict__ vA, float* __restrict__ vB) {
  int i = blockIdx.x * IBLK + threadIdx.x;
  if (i >= NPTS) return;
  float x2 = p2[2 * i + 0];
  float y2 = p2[2 * i + 1];
  float x3 = p3[3 * i + 0];
  float y3 = p3[3 * i + 1];
  float z3 = p3[3 * i + 2];
  rec[i] = make_float4(x2, y2, x3, y3);
  z3a[i] = z3;
  vA[i] = 1.0f;   // v0 = ones
  vB[i] = 0.0f;   // iter0 atomic target
}

// y[i] += (1/1024) * sum_j S(i,j) * v[j], j in this block's partition.
// Each thread owns IPT=4 i-rows (4 independent FMA chains, 4x j-load reuse).
// diff-form kept deliberately: dot-form needs a clamp vs sqrt(negative) that
// makes it op-count neutral. Also zeroes the dst-after-next buffer.
__global__ __launch_bounds__(IBLK) void matvec_kernel(
    const float4* __restrict__ rec, const float* __restrict__ z3a,
    const float* __restrict__ vsrc, float* __restrict__ vdst,
    float* __restrict__ vzero) {
  const int ib = blockIdx.x % NIBLK;
  const int jp = blockIdx.x / NIBLK;
  const int i0 = ib * ISPAN + threadIdx.x;

  float4 ri[IPT];
  float  zi[IPT];
  float  acc[IPT];
#pragma unroll
  for (int u = 0; u < IPT; ++u) {
    const int i = i0 + u * IBLK;
    ri[u]  = rec[i];
    zi[u]  = z3a[i];
    acc[u] = 0.0f;
    if (jp == 0) vzero[i] = 0.0f;   // prepare next-next iteration's dst
  }

  const int j0 = jp * JLEN;
#pragma unroll 4
  for (int jj = 0; jj < JLEN; ++jj) {
    const int j = j0 + jj;          // wave-uniform -> scalar/broadcast loads
    const float4 rj = rec[j];
    const float  zj = z3a[j];
    const float  vj = vsrc[j];
#pragma unroll
    for (int u = 0; u < IPT; ++u) {
      float dx = ri[u].x - rj.x, dy = ri[u].y - rj.y;
      float a  = fmaf(dy, dy, dx * dx);                     // ||dp2||^2
      float ex = ri[u].z - rj.z, ey = ri[u].w - rj.w, ez = zi[u] - zj;
      float b  = fmaf(ez, ez, fmaf(ey, ey, ex * ex));       // ||dp3||^2
      float s  = __builtin_amdgcn_sqrtf(a * b);             // bare v_sqrt_f32 (~1 ulp)
      // (d2-d3)^2 = a + b - 2*sqrt(ab);  S = max(0, 1 - 100*(a+b) + 200*sqrt(ab))
      float w  = fmaf(a + b, -100.0f, 1.0f);
      w = fmaf(s, 200.0f, w);
      w = fmaxf(w, 0.0f);
      acc[u] = fmaf(w, vj, acc[u]);
    }
  }
#pragma unroll
  for (int u = 0; u < IPT; ++u)
    atomicAdd(&vdst[i0 + u * IBLK], acc[u] * RESCALE);
}

// out = v / (||v||_2 + 1e-6), float32; each block redundantly computes the norm.
__global__ __launch_bounds__(256) void finalize_kernel(
    const float* __restrict__ v, float* __restrict__ out) {
  const int tid = threadIdx.x;
  float ss = 0.0f;
  for (int k = tid; k < NPTS; k += 256) {
    float x = v[k];
    ss = fmaf(x, x, ss);
  }
  for (int off = 32; off > 0; off >>= 1) ss += __shfl_down(ss, off, 64);
  __shared__ float wsum[4];
  if ((tid & 63) == 0) wsum[tid >> 6] = ss;
  __syncthreads();
  float tot = wsum[0] + wsum[1] + wsum[2] + wsum[3];
  float inv = 1.0f / (sqrtf(tot) + 1e-6f);
  int i = blockIdx.x * 256 + tid;
  out[i] = v[i] * inv;
}

extern "C" void kernel_launch(void* const* d_in, const int* in_sizes, int n_in,
                              void* d_out, int out_size, void* d_ws, size_t ws_size,
                              hipStream_t stream) {
  const float* p2 = (const float*)d_in[0];   // 6144 x 2, float32
  const float* p3 = (const float*)d_in[1];   // 6144 x 3, float32
  float* out = (float*)d_out;                // 6144, float32

  float* w = (float*)d_ws;
  float4* rec = (float4*)w;           // 6144 float4  -> 24576 floats
  float*  z3a = w + 24576;            // 6144
  float*  buf[3] = { w + 32768, w + 40960, w + 49152 };  // v triple-buffer

  prep_kernel<<<NPTS / IBLK, IBLK, 0, stream>>>(p2, p3, rec, z3a, buf[0], buf[1]);

  for (int k = 0; k < 10; ++k) {
    float* vsrc  = buf[k % 3];
    float* vdst  = buf[(k + 1) % 3];
    float* vzero = buf[(k + 2) % 3];
    matvec_kernel<<<NIBLK * JPART, IBLK, 0, stream>>>(rec, z3a, vsrc, vdst, vzero);
  }

  // after 10 iters, result is in buf[(9+1)%3] == buf[1]
  finalize_kernel<<<NPTS / 256, 256, 0, stream>>>(buf[1], out);
}

// Round 6
// 204.688 us; speedup vs baseline: 2.3457x; 1.2025x over previous
//
#include <hip/hip_runtime.h>
#include <hip/hip_bf16.h>

#define NPTS   6144
#define IPT    4                  // i's per thread (2 packed float2 chains)
#define NCH    (IPT / 2)          // packed chains per thread
#define IBLK   128                // threads per block
#define ISPAN  (IBLK * IPT)       // 512 i's per block
#define NIBLK  (NPTS / ISPAN)     // 12 i-blocks
#define JPART  384                // j-partitions -> 4608 blocks, ~9216 waves
#define JLEN   (NPTS / JPART)     // 16 j's per partition
#define RESCALE (1.0f / 1024.0f)  // per-iteration overflow guard (cancels at final normalize)

typedef float v2f __attribute__((ext_vector_type(2)));

// Pack f32 inputs into SoA for clean uniform loads; init v buffers.
__global__ __launch_bounds__(IBLK) void prep_kernel(
    const float* __restrict__ p2, const float* __restrict__ p3,
    float4* __restrict__ rec, float* __restrict__ z3a,
    float* __restrict__ vA, float* __restrict__ vB) {
  int i = blockIdx.x * IBLK + threadIdx.x;
  if (i >= NPTS) return;
  float x2 = p2[2 * i + 0];
  float y2 = p2[2 * i + 1];
  float x3 = p3[3 * i + 0];
  float y3 = p3[3 * i + 1];
  float z3 = p3[3 * i + 2];
  rec[i] = make_float4(x2, y2, x3, y3);
  z3a[i] = z3;
  vA[i] = 1.0f;   // v0 = ones
  vB[i] = 0.0f;   // iter0 atomic target
}

// y[i] += (1/1024) * sum_j S(i,j) * v[j], j in this block's partition.
// IPT=4 i-rows per thread arranged as 2 float2 chains so the backend can use
// packed dual-f32 (v_pk_fma_f32 etc.) — halves main-pipe issue slots/pair.
// Worst case it scalarizes to exactly the previous code. Also zeroes the
// dst-after-next buffer.
__global__ __launch_bounds__(IBLK) void matvec_kernel(
    const float4* __restrict__ rec, const float* __restrict__ z3a,
    const float* __restrict__ vsrc, float* __restrict__ vdst,
    float* __restrict__ vzero) {
  const int ib = blockIdx.x % NIBLK;
  const int jp = blockIdx.x / NIBLK;
  const int i0 = ib * ISPAN + threadIdx.x;

  v2f X2[NCH], Y2[NCH], X3[NCH], Y3[NCH], Z3[NCH], acc[NCH];
#pragma unroll
  for (int c = 0; c < NCH; ++c) {
    const int ia = i0 + (2 * c + 0) * IBLK;
    const int ib2 = i0 + (2 * c + 1) * IBLK;
    float4 ra = rec[ia], rb = rec[ib2];
    X2[c] = (v2f){ra.x, rb.x};
    Y2[c] = (v2f){ra.y, rb.y};
    X3[c] = (v2f){ra.z, rb.z};
    Y3[c] = (v2f){ra.w, rb.w};
    Z3[c] = (v2f){z3a[ia], z3a[ib2]};
    acc[c] = (v2f){0.0f, 0.0f};
    if (jp == 0) { vzero[ia] = 0.0f; vzero[ib2] = 0.0f; }
  }

  const v2f kM100 = (v2f){-100.0f, -100.0f};
  const v2f k200  = (v2f){ 200.0f,  200.0f};
  const v2f kOne  = (v2f){   1.0f,    1.0f};
  const v2f kZero = (v2f){   0.0f,    0.0f};

  const int j0 = jp * JLEN;
#pragma unroll 4
  for (int jj = 0; jj < JLEN; ++jj) {
    const int j = j0 + jj;          // wave-uniform -> scalar/broadcast loads
    const float4 rj = rec[j];
    const float  zj = z3a[j];
    const float  vj = vsrc[j];
#pragma unroll
    for (int c = 0; c < NCH; ++c) {
      v2f dx = X2[c] - rj.x, dy = Y2[c] - rj.y;
      v2f a  = __builtin_elementwise_fma(dy, dy, dx * dx);          // ||dp2||^2
      v2f ex = X3[c] - rj.z, ey = Y3[c] - rj.w, ez = Z3[c] - zj;
      v2f b  = __builtin_elementwise_fma(
                   ez, ez, __builtin_elementwise_fma(ey, ey, ex * ex)); // ||dp3||^2
      v2f ab = a * b;
      v2f s  = (v2f){__builtin_amdgcn_sqrtf(ab.x),
                     __builtin_amdgcn_sqrtf(ab.y)};                 // bare v_sqrt_f32
      // (d2-d3)^2 = a+b-2*sqrt(ab);  S = max(0, 1 - 100*(a+b) + 200*sqrt(ab))
      v2f w  = __builtin_elementwise_fma(a + b, kM100, kOne);
      w = __builtin_elementwise_fma(s, k200, w);
      w = __builtin_elementwise_max(w, kZero);
      acc[c] = __builtin_elementwise_fma(w, (v2f){vj, vj}, acc[c]);
    }
  }
#pragma unroll
  for (int c = 0; c < NCH; ++c) {
    atomicAdd(&vdst[i0 + (2 * c + 0) * IBLK], acc[c].x * RESCALE);
    atomicAdd(&vdst[i0 + (2 * c + 1) * IBLK], acc[c].y * RESCALE);
  }
}

// out = v / (||v||_2 + 1e-6), float32; each block redundantly computes the norm.
__global__ __launch_bounds__(256) void finalize_kernel(
    const float* __restrict__ v, float* __restrict__ out) {
  const int tid = threadIdx.x;
  float ss = 0.0f;
  for (int k = tid; k < NPTS; k += 256) {
    float x = v[k];
    ss = fmaf(x, x, ss);
  }
  for (int off = 32; off > 0; off >>= 1) ss += __shfl_down(ss, off, 64);
  __shared__ float wsum[4];
  if ((tid & 63) == 0) wsum[tid >> 6] = ss;
  __syncthreads();
  float tot = wsum[0] + wsum[1] + wsum[2] + wsum[3];
  float inv = 1.0f / (sqrtf(tot) + 1e-6f);
  int i = blockIdx.x * 256 + tid;
  out[i] = v[i] * inv;
}

extern "C" void kernel_launch(void* const* d_in, const int* in_sizes, int n_in,
                              void* d_out, int out_size, void* d_ws, size_t ws_size,
                              hipStream_t stream) {
  const float* p2 = (const float*)d_in[0];   // 6144 x 2, float32
  const float* p3 = (const float*)d_in[1];   // 6144 x 3, float32
  float* out = (float*)d_out;                // 6144, float32

  float* w = (float*)d_ws;
  float4* rec = (float4*)w;           // 6144 float4  -> 24576 floats
  float*  z3a = w + 24576;            // 6144
  float*  buf[3] = { w + 32768, w + 40960, w + 49152 };  // v triple-buffer

  prep_kernel<<<NPTS / IBLK, IBLK, 0, stream>>>(p2, p3, rec, z3a, buf[0], buf[1]);

  for (int k = 0; k < 10; ++k) {
    float* vsrc  = buf[k % 3];
    float* vdst  = buf[(k + 1) % 3];
    float* vzero = buf[(k + 2) % 3];
    matvec_kernel<<<NIBLK * JPART, IBLK, 0, stream>>>(rec, z3a, vsrc, vdst, vzero);
  }

  // after 10 iters, result is in buf[(9+1)%3] == buf[1]
  finalize_kernel<<<NPTS / 256, 256, 0, stream>>>(buf[1], out);
}

// Round 7
// 199.557 us; speedup vs baseline: 2.4060x; 1.0257x over previous
//
#include <hip/hip_runtime.h>
#include <hip/hip_bf16.h>

#define NPTS   6144
#define IPT    4                  // i's per thread (2 packed float2 chains)
#define NCH    (IPT / 2)          // packed chains per thread
#define IBLK   128                // threads per block
#define ISPAN  (IBLK * IPT)       // 512 i's per block
#define NIBLK  (NPTS / ISPAN)     // 12 i-blocks
#define JPART  384                // j-partitions -> 4608 blocks
#define JLEN   (NPTS / JPART)     // 16 j's per partition (all hoisted to regs)
#define RESCALE (1.0f / 1024.0f)  // per-iteration overflow guard (cancels at final normalize)

typedef float v2f __attribute__((ext_vector_type(2)));

// Pack f32 inputs into SoA for clean uniform loads; init v buffers.
__global__ __launch_bounds__(IBLK) void prep_kernel(
    const float* __restrict__ p2, const float* __restrict__ p3,
    float4* __restrict__ rec, float* __restrict__ z3a,
    float* __restrict__ vA, float* __restrict__ vB) {
  int i = blockIdx.x * IBLK + threadIdx.x;
  if (i >= NPTS) return;
  float x2 = p2[2 * i + 0];
  float y2 = p2[2 * i + 1];
  float x3 = p3[3 * i + 0];
  float y3 = p3[3 * i + 1];
  float z3 = p3[3 * i + 2];
  rec[i] = make_float4(x2, y2, x3, y3);
  z3a[i] = z3;
  vA[i] = 1.0f;   // v0 = ones
  vB[i] = 0.0f;   // iter0 atomic target
}

// y[i] += (1/1024) * sum_j S(i,j) * v[j], j in this block's partition.
// ALL j-side data (16 entries x 6 scalars, wave-uniform) is hoisted into
// registers before the loop and the jj loop is fully unrolled: the inner
// body is pure ALU (zero loads), one vmcnt wait per block. IPT=4 i-rows as
// 2 packed-f32 chains (v_pk_* dual-f32). Also zeroes the dst-after-next buf.
__global__ __launch_bounds__(IBLK) void matvec_kernel(
    const float4* __restrict__ rec, const float* __restrict__ z3a,
    const float* __restrict__ vsrc, float* __restrict__ vdst,
    float* __restrict__ vzero) {
  const int ib = blockIdx.x % NIBLK;
  const int jp = blockIdx.x / NIBLK;
  const int i0 = ib * ISPAN + threadIdx.x;

  // Hoist j-side (wave-uniform -> SGPR candidates)
  const int j0 = jp * JLEN;
  float4 RJ[JLEN];
  float  ZJ[JLEN], VJ[JLEN];
#pragma unroll
  for (int jj = 0; jj < JLEN; ++jj) {
    RJ[jj] = rec[j0 + jj];
    ZJ[jj] = z3a[j0 + jj];
    VJ[jj] = vsrc[j0 + jj];
  }

  v2f X2[NCH], Y2[NCH], X3[NCH], Y3[NCH], Z3[NCH], acc[NCH];
#pragma unroll
  for (int c = 0; c < NCH; ++c) {
    const int ia  = i0 + (2 * c + 0) * IBLK;
    const int ib2 = i0 + (2 * c + 1) * IBLK;
    float4 ra = rec[ia], rb = rec[ib2];
    X2[c] = (v2f){ra.x, rb.x};
    Y2[c] = (v2f){ra.y, rb.y};
    X3[c] = (v2f){ra.z, rb.z};
    Y3[c] = (v2f){ra.w, rb.w};
    Z3[c] = (v2f){z3a[ia], z3a[ib2]};
    acc[c] = (v2f){0.0f, 0.0f};
    if (jp == 0) { vzero[ia] = 0.0f; vzero[ib2] = 0.0f; }
  }

  const v2f kM100 = (v2f){-100.0f, -100.0f};
  const v2f k200  = (v2f){ 200.0f,  200.0f};
  const v2f kOne  = (v2f){   1.0f,    1.0f};
  const v2f kZero = (v2f){   0.0f,    0.0f};

#pragma unroll
  for (int jj = 0; jj < JLEN; ++jj) {
    const float4 rj = RJ[jj];
    const float  zj = ZJ[jj];
    const float  vj = VJ[jj];
#pragma unroll
    for (int c = 0; c < NCH; ++c) {
      v2f dx = X2[c] - rj.x, dy = Y2[c] - rj.y;
      v2f a  = __builtin_elementwise_fma(dy, dy, dx * dx);          // ||dp2||^2
      v2f ex = X3[c] - rj.z, ey = Y3[c] - rj.w, ez = Z3[c] - zj;
      v2f b  = __builtin_elementwise_fma(
                   ez, ez, __builtin_elementwise_fma(ey, ey, ex * ex)); // ||dp3||^2
      v2f ab = a * b;
      v2f s  = (v2f){__builtin_amdgcn_sqrtf(ab.x),
                     __builtin_amdgcn_sqrtf(ab.y)};                 // bare v_sqrt_f32
      // (d2-d3)^2 = a+b-2*sqrt(ab);  S = max(0, 1 - 100*(a+b) + 200*sqrt(ab))
      v2f w  = __builtin_elementwise_fma(a + b, kM100, kOne);
      w = __builtin_elementwise_fma(s, k200, w);
      w = __builtin_elementwise_max(w, kZero);
      acc[c] = __builtin_elementwise_fma(w, (v2f){vj, vj}, acc[c]);
    }
  }
#pragma unroll
  for (int c = 0; c < NCH; ++c) {
    atomicAdd(&vdst[i0 + (2 * c + 0) * IBLK], acc[c].x * RESCALE);
    atomicAdd(&vdst[i0 + (2 * c + 1) * IBLK], acc[c].y * RESCALE);
  }
}

// out = v / (||v||_2 + 1e-6), float32; each block redundantly computes the norm.
__global__ __launch_bounds__(256) void finalize_kernel(
    const float* __restrict__ v, float* __restrict__ out) {
  const int tid = threadIdx.x;
  float ss = 0.0f;
  for (int k = tid; k < NPTS; k += 256) {
    float x = v[k];
    ss = fmaf(x, x, ss);
  }
  for (int off = 32; off > 0; off >>= 1) ss += __shfl_down(ss, off, 64);
  __shared__ float wsum[4];
  if ((tid & 63) == 0) wsum[tid >> 6] = ss;
  __syncthreads();
  float tot = wsum[0] + wsum[1] + wsum[2] + wsum[3];
  float inv = 1.0f / (sqrtf(tot) + 1e-6f);
  int i = blockIdx.x * 256 + tid;
  out[i] = v[i] * inv;
}

extern "C" void kernel_launch(void* const* d_in, const int* in_sizes, int n_in,
                              void* d_out, int out_size, void* d_ws, size_t ws_size,
                              hipStream_t stream) {
  const float* p2 = (const float*)d_in[0];   // 6144 x 2, float32
  const float* p3 = (const float*)d_in[1];   // 6144 x 3, float32
  float* out = (float*)d_out;                // 6144, float32

  float* w = (float*)d_ws;
  float4* rec = (float4*)w;           // 6144 float4  -> 24576 floats
  float*  z3a = w + 24576;            // 6144
  float*  buf[3] = { w + 32768, w + 40960, w + 49152 };  // v triple-buffer

  prep_kernel<<<NPTS / IBLK, IBLK, 0, stream>>>(p2, p3, rec, z3a, buf[0], buf[1]);

  for (int k = 0; k < 10; ++k) {
    float* vsrc  = buf[k % 3];
    float* vdst  = buf[(k + 1) % 3];
    float* vzero = buf[(k + 2) % 3];
    matvec_kernel<<<NIBLK * JPART, IBLK, 0, stream>>>(rec, z3a, vsrc, vdst, vzero);
  }

  // after 10 iters, result is in buf[(9+1)%3] == buf[1]
  finalize_kernel<<<NPTS / 256, 256, 0, stream>>>(buf[1], out);
}